// Round 15
// baseline (176.430 us; speedup 1.0000x reference)
//
#include <hip/hip_runtime.h>
#include <stdint.h>

using bf16x8 = __attribute__((ext_vector_type(8))) short;
using f32x4  = __attribute__((ext_vector_type(4))) float;

__device__ __forceinline__ unsigned short f2bf(float f) {
  union { float f; uint32_t u; } v; v.f = f;
  uint32_t r = v.u + 0x7FFFu + ((v.u >> 16) & 1u);
  return (unsigned short)(r >> 16);
}
__device__ __forceinline__ uint32_t pk2(float a, float b) {
  return (uint32_t)f2bf(a) | ((uint32_t)f2bf(b) << 16);
}
__device__ __forceinline__ float bf2f(unsigned short s) {
  union { uint32_t u; float f; } v; v.u = ((uint32_t)s) << 16;
  return v.f;
}
__device__ __forceinline__ f32x4 mfma16(bf16x8 a, bf16x8 b, f32x4 c) {
  return __builtin_amdgcn_mfma_f32_16x16x32_bf16(a, b, c, 0, 0, 0);
}

// ---------------- Kernel 1 (merged prep): lnstats | wprep | w3prep ----------------
__global__ __launch_bounds__(256) void k_prep(
    const float* __restrict__ xl, const float* __restrict__ xr,
    const float* __restrict__ lnwl, const float* __restrict__ lnbl,
    const float* __restrict__ lnwr, const float* __restrict__ lnbr,
    const float* __restrict__ Wl1, const float* __restrict__ bl1,
    const float* __restrict__ Wr1, const float* __restrict__ br1,
    const float* __restrict__ Wl2, const float* __restrict__ Wr2,
    const float* __restrict__ Wl3, const float* __restrict__ Wr3,
    float* __restrict__ muW, float* __restrict__ rsW,
    unsigned short* __restrict__ Wq, unsigned short* __restrict__ Wv,
    float* __restrict__ bqW, unsigned short* __restrict__ W3bf)
{
  const int gbid = blockIdx.x;
  const int t = threadIdx.x;
  __shared__ float red[4];

  if (gbid < 256) {
    const int bx = gbid;
    const int side = bx >> 7, rem = bx & 127;
    const int b = rem >> 1, half = rem & 1;
    const float* x = (side ? xr : xl) + (size_t)b * 131072 + half * 512;
    const int px = t * 2;
    float s0=0, s1=0, q0=0, q1=0;
#pragma unroll 4
    for (int c = 0; c < 128; ++c) {
      const float2 v = *(const float2*)(x + c*1024 + px);
      s0 += v.x; q0 += v.x*v.x;
      s1 += v.y; q1 += v.y*v.y;
    }
    const int o = (side*64 + b)*1024 + half*512 + px;
    float2 mu, rs;
    mu.x = s0*(1.0f/128.0f); mu.y = s1*(1.0f/128.0f);
    rs.x = rsqrtf(fmaxf(q0*(1.0f/128.0f) - mu.x*mu.x, 0.0f) + 1e-6f);
    rs.y = rsqrtf(fmaxf(q1*(1.0f/128.0f) - mu.y*mu.y, 0.0f) + 1e-6f);
    *(float2*)(muW + o) = mu;
    *(float2*)(rsW + o) = rs;
  } else if (gbid < 512) {
    const int bx = gbid - 256;
    const int side = bx >> 7, co = bx & 127;
    const float* W1  = side ? Wr1 : Wl1;
    const float* W2  = side ? Wr2 : Wl2;
    const float* b1  = side ? br1 : bl1;
    const float* lnw = side ? lnwr : lnwl;
    const float* lnb = side ? lnbr : lnbl;
    const int ci = t >> 1;
    const float lw = lnw[ci], lb = lnb[ci];

    const size_t dsto = (size_t)(side*32 + (t>>3))*8192 + (size_t)co*64 + (t&7)*8;

    const float* src1 = W1 + (size_t)co*2048 + t*8;
    const float4 a0 = *(const float4*)(src1);
    const float4 a1 = *(const float4*)(src1 + 4);
    float part = (a0.x+a0.y+a0.z+a0.w + a1.x+a1.y+a1.z+a1.w) * lb;
    uint4 pkq;
    pkq.x = pk2(a0.x*lw, a0.y*lw); pkq.y = pk2(a0.z*lw, a0.w*lw);
    pkq.z = pk2(a1.x*lw, a1.y*lw); pkq.w = pk2(a1.z*lw, a1.w*lw);
    *(uint4*)(Wq + dsto) = pkq;

    const float* src2 = W2 + (size_t)co*2048 + t*8;
    const float4 c0 = *(const float4*)(src2);
    const float4 c1 = *(const float4*)(src2 + 4);
    uint4 pkv;
    pkv.x = pk2(c0.x, c0.y); pkv.y = pk2(c0.z, c0.w);
    pkv.z = pk2(c1.x, c1.y); pkv.w = pk2(c1.z, c1.w);
    *(uint4*)(Wv + dsto) = pkv;

    float v = part;
    v += __shfl_down(v, 32, 64); v += __shfl_down(v, 16, 64);
    v += __shfl_down(v, 8, 64);  v += __shfl_down(v, 4, 64);
    v += __shfl_down(v, 2, 64);  v += __shfl_down(v, 1, 64);
    if ((t & 63) == 0) red[t >> 6] = v;
    __syncthreads();
    if (t == 0) bqW[side*128 + co] = b1[co] + red[0] + red[1] + red[2] + red[3];
  } else {
    const int b = gbid - 512;
    const float* src = (b < 256 ? Wl3 : Wr3) + (size_t)(b & 255) * 1024;
    const float4 v = *(const float4*)(src + t*4);
    *(uint2*)(W3bf + (size_t)b*1024 + t*4) = make_uint2(pk2(v.x, v.y), pk2(v.z, v.w));
  }
}

// ---------------- Kernel 2: conv GEMM, split-K x4, direct staging ----------------
__global__ __launch_bounds__(256) void k_conv(
    const float* __restrict__ xl, const float* __restrict__ xr,
    const unsigned short* __restrict__ Wq, const unsigned short* __restrict__ Wv,
    const float* __restrict__ muW, const float* __restrict__ rsW,
    unsigned short* __restrict__ Cpart)
{
  const int bid = blockIdx.x;
  const int ks = bid & 3;
  const int img = (bid >> 2) & 63;
  const int ctype = bid >> 8;
  const int side = ctype & 1;
  const bool isQ = ctype < 2;
  const float* x = (side ? xr : xl) + (size_t)img * 131072;
  const unsigned short* Bsrc = (isQ ? Wq : Wv) + (size_t)side * 262144;

  const int t = threadIdx.x;
  const int w = t >> 6, l = t & 63, lo = l & 15, g = l >> 4;

  __shared__ __align__(16) unsigned char lds[24576];
  unsigned char* A = lds;
  unsigned char* B = lds + 8192;

  const int cl   = t >> 6;
  const int px0  = (t & 63) * 16;
  const int y    = px0 >> 5;
  const int wr   = y & 3;
  const int pbase = (y >> 2)*8 + ((px0 & 31) >> 2);

  float4 mu4[4], rs4[4];
  if (isQ) {
    const int o = (side*64 + img)*1024 + px0;
#pragma unroll
    for (int i = 0; i < 4; ++i) {
      mu4[i] = *(const float4*)(muW + o + 4*i);
      rs4[i] = *(const float4*)(rsW + o + 4*i);
    }
  }

  const int cout = t >> 1, part = t & 1;
  const int keyB = ((cout ^ (cout >> 3)) & 7) << 4;

  f32x4 acc[4][2];
#pragma unroll
  for (int a = 0; a < 4; ++a) { acc[a][0] = (f32x4)0.0f; acc[a][1] = (f32x4)0.0f; }

  for (int it = 0; it < 8; ++it) {
    const int kb = ks*8 + it;
    __syncthreads();
    {
      const float* xs = x + (size_t)(kb*4 + cl)*1024 + px0;
#pragma unroll
      for (int i = 0; i < 4; ++i) {
        float4 v = *(const float4*)(xs + 4*i);
        if (isQ) {
          v.x = (v.x - mu4[i].x)*rs4[i].x; v.y = (v.y - mu4[i].y)*rs4[i].y;
          v.z = (v.z - mu4[i].z)*rs4[i].z; v.w = (v.w - mu4[i].w)*rs4[i].w;
        }
        const int p = pbase + i;
        int dst = p*128 + cl*32 + wr*8;
        dst ^= ((p ^ (p >> 3)) & 7) << 4;
        *(uint2*)(A + dst) = make_uint2(pk2(v.x, v.y), pk2(v.z, v.w));
      }
    }
    {
      const unsigned short* bs = Bsrc + (size_t)kb*8192 + t*32;
#pragma unroll
      for (int i = 0; i < 4; ++i) {
        const bf16x8 v = *(const bf16x8*)(bs + i*8);
        *(bf16x8*)(B + cout*128 + ((part*64 + i*16) ^ keyB)) = v;
      }
    }
    __syncthreads();
    bf16x8 af[4][2], bfr[2][2];
#pragma unroll
    for (int mf = 0; mf < 4; ++mf) {
      const int row = mf*16 + lo;
      const int key = ((row ^ (row >> 3)) & 7) << 4;
#pragma unroll
      for (int kc = 0; kc < 2; ++kc)
        af[mf][kc] = *(const bf16x8*)(A + row*128 + ((kc*64 + g*16) ^ key));
    }
#pragma unroll
    for (int nf = 0; nf < 2; ++nf) {
      const int row = w*32 + nf*16 + lo;
      const int key = ((row ^ (row >> 3)) & 7) << 4;
#pragma unroll
      for (int kc = 0; kc < 2; ++kc)
        bfr[nf][kc] = *(const bf16x8*)(B + row*128 + ((kc*64 + g*16) ^ key));
    }
    __builtin_amdgcn_s_setprio(1);
#pragma unroll
    for (int kc = 0; kc < 2; ++kc)
#pragma unroll
      for (int nf = 0; nf < 2; ++nf)
#pragma unroll
        for (int mf = 0; mf < 4; ++mf)
          acc[mf][nf] = mfma16(af[mf][kc], bfr[nf][kc], acc[mf][nf]);
    __builtin_amdgcn_s_setprio(0);
  }

  unsigned short* Cp = Cpart + (size_t)bid * 8192;
#pragma unroll
  for (int mf = 0; mf < 4; ++mf)
#pragma unroll
    for (int nf = 0; nf < 2; ++nf) {
      const int c = w*32 + nf*16 + lo;
      const int p0 = mf*16 + g*4;
      *(uint2*)(Cp + c*64 + p0) =
          make_uint2(pk2(acc[mf][nf][0], acc[mf][nf][1]),
                     pk2(acc[mf][nf][2], acc[mf][nf][3]));
    }
}

// ---------------- Kernel 2b: combine conv split-K partials ----------------
// Q scale includes log2(e) fold: sqrt-scale * log2(e) = 0.12625283
__global__ __launch_bounds__(256) void k_convred(
    const unsigned short* __restrict__ Cpart,
    const float* __restrict__ bqW,
    const float* __restrict__ bl2, const float* __restrict__ br2,
    const float* __restrict__ pos,
    unsigned short* __restrict__ Qbf, unsigned short* __restrict__ Vtbf)
{
  const int bid2 = blockIdx.x;
  const int ctype = bid2 >> 6, img = bid2 & 63;
  const int side = ctype & 1;
  const bool isQ = ctype < 2;
  const int t = threadIdx.x;

  __shared__ float S[64][130];

  const int c = t >> 1, p0 = (t & 1) * 32;
  {
    float acc[32];
#pragma unroll
    for (int j = 0; j < 32; ++j) acc[j] = 0.f;
#pragma unroll
    for (int s = 0; s < 4; ++s) {
      const unsigned short* Cp = Cpart + ((size_t)(bid2*4 + s))*8192 + c*64 + p0;
#pragma unroll
      for (int j8 = 0; j8 < 4; ++j8) {
        const bf16x8 v = *(const bf16x8*)(Cp + j8*8);
#pragma unroll
        for (int e = 0; e < 8; ++e)
          acc[j8*8 + e] += bf2f((unsigned short)v[e]);
      }
    }
#pragma unroll
    for (int j = 0; j < 32; ++j) S[p0 + j][c] = acc[j];
  }
  __syncthreads();

  if (isQ) {
    const float* bq = bqW + side*128;
    const int p = t >> 2, c0 = (t & 3) * 32;
    const int rot = (t & 3) * 4;
    uint32_t pk[16];
#pragma unroll
    for (int j2 = 0; j2 < 16; ++j2) {
      const int jj = (j2 + rot) & 15;
      const int ca = c0 + jj*2;
      const float2 sv = *(const float2*)(&S[p][ca]);
      const float va = (sv.x + bq[ca]     + pos[ca*64 + p])     * 0.12625283f;
      const float vb = (sv.y + bq[ca + 1] + pos[(ca+1)*64 + p]) * 0.12625283f;
      pk[jj] = pk2(va, vb);
    }
    unsigned short* Qo = Qbf + (size_t)side*524288 + ((size_t)(img*64 + p))*128 + c0;
    *(uint4*)(Qo)      = make_uint4(pk[0],  pk[1],  pk[2],  pk[3]);
    *(uint4*)(Qo + 8)  = make_uint4(pk[4],  pk[5],  pk[6],  pk[7]);
    *(uint4*)(Qo + 16) = make_uint4(pk[8],  pk[9],  pk[10], pk[11]);
    *(uint4*)(Qo + 24) = make_uint4(pk[12], pk[13], pk[14], pk[15]);
  } else {
    const float* b2 = side ? br2 : bl2;
    const float bb = b2[c];
    uint32_t pk[16];
#pragma unroll
    for (int j2 = 0; j2 < 16; ++j2) {
      const int pa = p0 + j2*2;
      const float va = S[pa][c]     + bb + pos[c*64 + pa];
      const float vb = S[pa + 1][c] + bb + pos[c*64 + pa + 1];
      pk[j2] = pk2(va, vb);
    }
    unsigned short* Vo = Vtbf + (size_t)side*524288 + (size_t)c*4096 + img*64 + p0;
    *(uint4*)(Vo)      = make_uint4(pk[0],  pk[1],  pk[2],  pk[3]);
    *(uint4*)(Vo + 8)  = make_uint4(pk[4],  pk[5],  pk[6],  pk[7]);
    *(uint4*)(Vo + 16) = make_uint4(pk[8],  pk[9],  pk[10], pk[11]);
    *(uint4*)(Vo + 24) = make_uint4(pk[12], pk[13], pk[14], pk[15]);
  }
}

// ---------------- Kernel 3: cross-attention, split-K x8, single-buf, 4 blocks/CU ----------------
// grid 1024: bid = qb*16 + dir*8 + ks. bid%8 = ks -> each XCD serves one ks slice.
__global__ __launch_bounds__(256, 4) void k_attn(
    const unsigned short* __restrict__ Qbf,
    const unsigned short* __restrict__ Vtbf,
    float* __restrict__ Opart,   // [2][64][8][64][128] f32
    float* __restrict__ Lpart)   // [2][64][8][64] f32
{
  const int bid = blockIdx.x;
  const int ks  = bid & 7;
  const int dir = (bid >> 3) & 1;
  const int qb  = bid >> 4;
  const unsigned short* Qp = Qbf  + (size_t)dir*524288;
  const unsigned short* Kp = Qbf  + (size_t)(1-dir)*524288;
  const unsigned short* Vp = Vtbf + (size_t)(1-dir)*524288;

  const int t = threadIdx.x;
  const int w = t >> 6, l = t & 63, lo = l & 15, g = l >> 4;

  // [0,16K) K ; [16K,32K) V ; [32K,40K) P. lred overlays K after the loop.
  __shared__ __align__(16) unsigned char lds[40960];
  unsigned char* Kb = lds;
  unsigned char* Vb = lds + 16384;
  unsigned char* Pb = lds + 32768;
  float* lred = (float*)lds;   // [4][64], used after loop only

  bf16x8 aq[4][4];
#pragma unroll
  for (int mf = 0; mf < 4; ++mf)
#pragma unroll
    for (int kc = 0; kc < 4; ++kc)
      aq[mf][kc] = *(const bf16x8*)(Qp + (size_t)(qb*64 + mf*16 + lo)*128 + kc*32 + g*8);

  f32x4 o[4][2];
#pragma unroll
  for (int a = 0; a < 4; ++a) { o[a][0] = (f32x4)0.0f; o[a][1] = (f32x4)0.0f; }
  float ls[4] = {0.f, 0.f, 0.f, 0.f};

  const int kt0 = ks * 8;

  const int ksrcBase = t ^ ((t >> 4) & 7);
  const int vc    = t >> 3;
  const int vi16  = (t & 7) * 16;
  const int vsoff = (vi16 ^ (((t >> 3) & 7) << 4)) >> 1;

  // prologue: stage tile 0 directly
  {
    const uint4* src = (const uint4*)(Kp + (size_t)kt0*8192);
#pragma unroll
    for (int j = 0; j < 4; ++j)
      *(uint4*)(Kb + (t + 256*j)*16) = src[ksrcBase + 256*j];
#pragma unroll
    for (int j = 0; j < 4; ++j) {
      const int c = vc + 32*j;
      *(uint4*)(Vb + c*128 + vi16) =
          *(const uint4*)(Vp + (size_t)c*4096 + kt0*64 + vsoff);
    }
  }
  __syncthreads();

  for (int it = 0; it < 8; ++it) {
    // issue next-tile loads into named registers
    uint4 kr0, kr1, kr2, kr3, vr0, vr1, vr2, vr3;
    if (it < 7) {
      const int kt = kt0 + it + 1;
      const uint4* src = (const uint4*)(Kp + (size_t)kt*8192);
      kr0 = src[ksrcBase];
      kr1 = src[ksrcBase + 256];
      kr2 = src[ksrcBase + 512];
      kr3 = src[ksrcBase + 768];
      const unsigned short* vsrc = Vp + (size_t)kt*64 + vsoff;
      vr0 = *(const uint4*)(vsrc + (size_t)(vc     )*4096);
      vr1 = *(const uint4*)(vsrc + (size_t)(vc + 32)*4096);
      vr2 = *(const uint4*)(vsrc + (size_t)(vc + 64)*4096);
      vr3 = *(const uint4*)(vsrc + (size_t)(vc + 96)*4096);
    }

    // QK^T (swapped: A=K rows, B=Q rows): s[mf] = S[k=w*16+g*4+rr][q=mf*16+lo]
    f32x4 s[4];
    s[0] = (f32x4)0.0f; s[1] = (f32x4)0.0f; s[2] = (f32x4)0.0f; s[3] = (f32x4)0.0f;
    const int krow = w*16 + lo;
    const int keyk = (krow & 7) << 4;
    __builtin_amdgcn_s_setprio(1);
#pragma unroll
    for (int kc = 0; kc < 4; ++kc) {
      const bf16x8 bk = *(const bf16x8*)(Kb + krow*256 + ((kc*64 + g*16) ^ keyk));
#pragma unroll
      for (int mf = 0; mf < 4; ++mf)
        s[mf] = mfma16(bk, aq[mf][kc], s[mf]);
    }
    __builtin_amdgcn_s_setprio(0);

    // exp2 (log2e folded into Q scale), packed P write
#pragma unroll
    for (int mf = 0; mf < 4; ++mf) {
      const float e0 = exp2f(s[mf][0]);
      const float e1 = exp2f(s[mf][1]);
      const float e2 = exp2f(s[mf][2]);
      const float e3 = exp2f(s[mf][3]);
      ls[mf] += (e0 + e1) + (e2 + e3);
      const int q = mf*16 + lo;
      const int koff = (w*32 + g*8) ^ ((q & 7) << 4);
      *(uint2*)(Pb + q*128 + koff) = make_uint2(pk2(e0, e1), pk2(e2, e3));
    }
    __syncthreads();   // A: P visible, K consumed by all waves

    // PV
    __builtin_amdgcn_s_setprio(1);
#pragma unroll
    for (int kd = 0; kd < 2; ++kd) {
      bf16x8 pa[4];
#pragma unroll
      for (int mf = 0; mf < 4; ++mf) {
        const int q = mf*16 + lo;
        pa[mf] = *(const bf16x8*)(Pb + q*128 + ((kd*64 + g*16) ^ ((q & 7) << 4)));
      }
#pragma unroll
      for (int nf = 0; nf < 2; ++nf) {
        const int c = w*32 + nf*16 + lo;
        const bf16x8 bv = *(const bf16x8*)(Vb + c*128 + ((kd*64 + g*16) ^ ((c & 7) << 4)));
#pragma unroll
        for (int mf = 0; mf < 4; ++mf)
          o[mf][nf] = mfma16(pa[mf], bv, o[mf][nf]);
      }
    }
    __builtin_amdgcn_s_setprio(0);
    __syncthreads();   // B: V and P consumed by all waves

    if (it < 7) {
      *(uint4*)(Kb + (t      )*16) = kr0;
      *(uint4*)(Kb + (t + 256)*16) = kr1;
      *(uint4*)(Kb + (t + 512)*16) = kr2;
      *(uint4*)(Kb + (t + 768)*16) = kr3;
      *(uint4*)(Vb + (vc     )*128 + vi16) = vr0;
      *(uint4*)(Vb + (vc + 32)*128 + vi16) = vr1;
      *(uint4*)(Vb + (vc + 64)*128 + vi16) = vr2;
      *(uint4*)(Vb + (vc + 96)*128 + vi16) = vr3;
      __syncthreads(); // C: new K/V visible
    }
  }

  // denominator: ls[mf] holds partials for q=mf*16+lo over this wave's keys
#pragma unroll
  for (int mf = 0; mf < 4; ++mf) {
    float v = ls[mf];
    v += __shfl_xor(v, 16, 64);
    v += __shfl_xor(v, 32, 64);
    if (l < 16) lred[w*64 + mf*16 + lo] = v;
  }
  __syncthreads();

  float* Ob = Opart + (((size_t)dir*64 + qb)*8 + ks)*64*128;
#pragma unroll
  for (int mf = 0; mf < 4; ++mf)
#pragma unroll
    for (int nf = 0; nf < 2; ++nf) {
      const int c = w*32 + nf*16 + lo;
#pragma unroll
      for (int rr = 0; rr < 4; ++rr) {
        const int q = mf*16 + g*4 + rr;
        Ob[q*128 + c] = o[mf][nf][rr];
      }
    }
  if (t < 64)
    Lpart[(((size_t)dir*64 + qb)*8 + ks)*64 + t] =
        lred[t] + lred[64 + t] + lred[128 + t] + lred[192 + t];
}

// ---------------- Kernel 3b: combine split-K x8 partials -> F bf16 ----------------
__global__ __launch_bounds__(256) void k_reduce(
    const float* __restrict__ Opart, const float* __restrict__ Lpart,
    unsigned short* __restrict__ Fbf)
{
  const int bid = blockIdx.x;
  const int dir = bid >> 7, rb = bid & 127;
  const int t = threadIdx.x;
  const int qr = t >> 3;
  const int cs = (t & 7) * 16;
  const int r  = rb*32 + qr;
  const int qb = r >> 6, q = r & 63;
  const size_t pb = ((size_t)dir*64 + qb)*8;
  float acc[16];
#pragma unroll
  for (int i = 0; i < 16; ++i) acc[i] = 0.f;
  float lsum = 0.f;
#pragma unroll
  for (int s = 0; s < 8; ++s) {
    const float* Ob = Opart + ((pb + s)*64 + q)*128 + cs;
#pragma unroll
    for (int i = 0; i < 16; i += 4) {
      const float4 v = *(const float4*)(Ob + i);
      acc[i] += v.x; acc[i+1] += v.y; acc[i+2] += v.z; acc[i+3] += v.w;
    }
    lsum += Lpart[(pb + s)*64 + q];
  }
  const float inv = 1.0f / lsum;
  uint32_t pkw[8];
#pragma unroll
  for (int i = 0; i < 8; ++i) pkw[i] = pk2(acc[2*i]*inv, acc[2*i+1]*inv);
  unsigned short* Fo = Fbf + (size_t)dir*524288 + (size_t)r*128 + cs;
  *(uint4*)(Fo)     = make_uint4(pkw[0], pkw[1], pkw[2], pkw[3]);
  *(uint4*)(Fo + 8) = make_uint4(pkw[4], pkw[5], pkw[6], pkw[7]);
}

// ---------------- Kernel 4: projection + pixel-shuffle + residual ----------------
__global__ __launch_bounds__(256) void k_proj(
    const unsigned short* __restrict__ Fbf,
    const unsigned short* __restrict__ W3bf,
    const float* __restrict__ bl3, const float* __restrict__ br3,
    const float* __restrict__ beta, const float* __restrict__ gamma,
    const float* __restrict__ xl, const float* __restrict__ xr,
    float* __restrict__ out)
{
  const int nb = blockIdx.x, mb = blockIdx.y, side = blockIdx.z;
  const unsigned short* F  = Fbf + (size_t)side*524288 + (size_t)mb*8192;
  const unsigned short* W3 = W3bf + (size_t)side*262144 + (size_t)nb*16384;
  const float* b3  = (side ? br3 : bl3) + nb*128;
  const float* scl = side ? gamma : beta;
  const float* xin = (side ? xr : xl) + (size_t)mb*131072;
  float* op = out + (size_t)side*8388608 + (size_t)mb*131072;

  const int t = threadIdx.x;
  const int w = t >> 6, l = t & 63, lo = l & 15, g = l >> 4;

  __shared__ __align__(16) unsigned char lds[49152];
  unsigned char* Ft = lds;
  unsigned char* B3 = lds + 16384;
  float* Sf = (float*)lds;

  {
    const uint4* src = (const uint4*)F;
#pragma unroll
    for (int j = 0; j < 4; ++j) {
      const int idx = t + 256*j;
      const int dst = idx*16;
      const int row = dst >> 8;
      *(uint4*)(Ft + dst) = src[(dst ^ ((row & 7) << 4)) >> 4];
    }
  }
  {
    const int nl = t >> 1, half = t & 1;
    const unsigned short* wsrc = W3 + (size_t)nl*128 + half*64;
#pragma unroll
    for (int ch = 0; ch < 8; ++ch) {
      const uint4 v = *(const uint4*)(wsrc + ch*8);
      const int inrow = (half*128 + ch*16) ^ ((nl & 7) << 4);
      *(uint4*)(B3 + nl*256 + inrow) = v;
    }
  }
  __syncthreads();

  f32x4 acc[4][2];
#pragma unroll
  for (int a=0;a<4;a++) { acc[a][0] = (f32x4)0.0f; acc[a][1] = (f32x4)0.0f; }

  bf16x8 af[4][4];
#pragma unroll
  for (int mf = 0; mf < 4; ++mf) {
    const int row = mf*16 + lo;
#pragma unroll
    for (int kc = 0; kc < 4; ++kc)
      af[mf][kc] = *(const bf16x8*)(Ft + row*256 + ((kc*64 + g*16) ^ ((row & 7) << 4)));
  }
#pragma unroll
  for (int kc = 0; kc < 4; ++kc)
#pragma unroll
    for (int nf = 0; nf < 2; ++nf) {
      const int n = w*32 + nf*16 + lo;
      const bf16x8 bb = *(const bf16x8*)(B3 + n*256 + ((kc*64 + g*16) ^ ((n & 7) << 4)));
#pragma unroll
      for (int mf = 0; mf < 4; ++mf)
        acc[mf][nf] = mfma16(af[mf][kc], bb, acc[mf][nf]);
    }

  __syncthreads();

  {
    const int r4 = (lo >> 2) & 3, sc = lo & 3;
#pragma unroll
    for (int nf = 0; nf < 2; ++nf) {
      const int cl = w*2 + nf;
      const int n16 = w*32 + nf*16 + lo;
      const float scc = scl[nb*8 + cl];
      const float bb3 = b3[n16];
#pragma unroll
      for (int mf = 0; mf < 4; ++mf)
#pragma unroll
        for (int rr = 0; rr < 4; ++rr) {
          const int pi = mf*16 + g*4 + rr;
          const int h = pi >> 3, wc = pi & 7;
          Sf[cl*1032 + h*128 + r4*32 + wc*4 + sc] = scc*(acc[mf][nf][rr] + bb3);
        }
    }
  }
  __syncthreads();

#pragma unroll
  for (int j = 0; j < 8; ++j) {
    const int pix = t*4;
    const float4 s = *(const float4*)(Sf + j*1032 + pix);
    const size_t gaddr = (size_t)(nb*8 + j)*1024 + pix;
    const float4 xv = *(const float4*)(xin + gaddr);
    float4 r;
    r.x = xv.x + s.x; r.y = xv.y + s.y; r.z = xv.z + s.z; r.w = xv.w + s.w;
    *(float4*)(op + gaddr) = r;
  }
}

extern "C" void kernel_launch(void* const* d_in, const int* in_sizes, int n_in,
                              void* d_out, int out_size, void* d_ws, size_t ws_size,
                              hipStream_t stream) {
  (void)in_sizes; (void)n_in; (void)out_size; (void)ws_size;
  const float* xl   = (const float*)d_in[0];
  const float* xr   = (const float*)d_in[1];
  const float* lnwl = (const float*)d_in[2];
  const float* lnbl = (const float*)d_in[3];
  const float* lnwr = (const float*)d_in[4];
  const float* lnbr = (const float*)d_in[5];
  const float* Wl1  = (const float*)d_in[6];
  const float* bl1  = (const float*)d_in[7];
  const float* Wr1  = (const float*)d_in[8];
  const float* br1  = (const float*)d_in[9];
  const float* Wl2  = (const float*)d_in[10];
  const float* bl2  = (const float*)d_in[11];
  const float* Wr2  = (const float*)d_in[12];
  const float* br2  = (const float*)d_in[13];
  const float* pos  = (const float*)d_in[14];
  const float* beta = (const float*)d_in[15];
  const float* gamma= (const float*)d_in[16];
  const float* Wl3  = (const float*)d_in[17];
  const float* bl3  = (const float*)d_in[18];
  const float* Wr3  = (const float*)d_in[19];
  const float* br3  = (const float*)d_in[20];

  float* muW = (float*)d_ws;                            // [2][64][1024]
  float* rsW = muW + 131072;                            // [2][64][1024]
  float* bqW = rsW + 131072;                            // [2][128]
  unsigned short* Wq   = (unsigned short*)(bqW + 256);  // [2][32][128][64]
  unsigned short* Wv   = Wq + 524288;                   // [2][32][128][64]
  unsigned short* Qbf  = Wv + 524288;                   // [2][4096][128]
  unsigned short* Vtbf = Qbf + 1048576;                 // [2][128][4096]
  unsigned short* Fbf  = Vtbf + 1048576;                // [2][4096][128]
  unsigned short* W3bf = Fbf + 1048576;                 // [2][2048][128]
  unsigned short* Cpart = W3bf + 524288;                // [1024][128][64] bf16 (16.8MB)
  float* Opart = (float*)Cpart;                         // alias: [2][64][8][64][128] f32 (33.5MB)
  float* Lpart = Opart + 8388608;                       // [2][64][8][64] f32

  k_prep<<<1024, 256, 0, stream>>>(xl, xr, lnwl, lnbl, lnwr, lnbr,
      Wl1, bl1, Wr1, br1, Wl2, Wr2, Wl3, Wr3, muW, rsW, Wq, Wv, bqW, W3bf);
  k_conv<<<1024, 256, 0, stream>>>(xl, xr, Wq, Wv, muW, rsW, Cpart);
  k_convred<<<256, 256, 0, stream>>>(Cpart, bqW, bl2, br2, pos, Qbf, Vtbf);
  k_attn<<<1024, 256, 0, stream>>>(Qbf, Vtbf, Opart, Lpart);
  k_reduce<<<256, 256, 0, stream>>>(Opart, Lpart, Fbf);
  k_proj<<<dim3(16, 64, 2), 256, 0, stream>>>(Fbf, W3bf, bl3, br3,
      beta, gamma, xl, xr, (float*)d_out);
}

// Round 16
// 122.289 us; speedup vs baseline: 1.4427x; 1.4427x over previous
//
#include <hip/hip_runtime.h>
#include <stdint.h>

using bf16x8 = __attribute__((ext_vector_type(8))) short;
using f32x4  = __attribute__((ext_vector_type(4))) float;

__device__ __forceinline__ unsigned short f2bf(float f) {
  union { float f; uint32_t u; } v; v.f = f;
  uint32_t r = v.u + 0x7FFFu + ((v.u >> 16) & 1u);
  return (unsigned short)(r >> 16);
}
__device__ __forceinline__ uint32_t pk2(float a, float b) {
  return (uint32_t)f2bf(a) | ((uint32_t)f2bf(b) << 16);
}
__device__ __forceinline__ float bf2f(unsigned short s) {
  union { uint32_t u; float f; } v; v.u = ((uint32_t)s) << 16;
  return v.f;
}
__device__ __forceinline__ f32x4 mfma16(bf16x8 a, bf16x8 b, f32x4 c) {
  return __builtin_amdgcn_mfma_f32_16x16x32_bf16(a, b, c, 0, 0, 0);
}

// ---------------- Kernel 1 (merged prep): lnstats | wprep | w3prep ----------------
__global__ __launch_bounds__(256) void k_prep(
    const float* __restrict__ xl, const float* __restrict__ xr,
    const float* __restrict__ lnwl, const float* __restrict__ lnbl,
    const float* __restrict__ lnwr, const float* __restrict__ lnbr,
    const float* __restrict__ Wl1, const float* __restrict__ bl1,
    const float* __restrict__ Wr1, const float* __restrict__ br1,
    const float* __restrict__ Wl2, const float* __restrict__ Wr2,
    const float* __restrict__ Wl3, const float* __restrict__ Wr3,
    float* __restrict__ muW, float* __restrict__ rsW,
    unsigned short* __restrict__ Wq, unsigned short* __restrict__ Wv,
    float* __restrict__ bqW, unsigned short* __restrict__ W3bf)
{
  const int gbid = blockIdx.x;
  const int t = threadIdx.x;
  __shared__ float red[4];

  if (gbid < 256) {
    const int bx = gbid;
    const int side = bx >> 7, rem = bx & 127;
    const int b = rem >> 1, half = rem & 1;
    const float* x = (side ? xr : xl) + (size_t)b * 131072 + half * 512;
    const int px = t * 2;
    float s0=0, s1=0, q0=0, q1=0;
#pragma unroll 4
    for (int c = 0; c < 128; ++c) {
      const float2 v = *(const float2*)(x + c*1024 + px);
      s0 += v.x; q0 += v.x*v.x;
      s1 += v.y; q1 += v.y*v.y;
    }
    const int o = (side*64 + b)*1024 + half*512 + px;
    float2 mu, rs;
    mu.x = s0*(1.0f/128.0f); mu.y = s1*(1.0f/128.0f);
    rs.x = rsqrtf(fmaxf(q0*(1.0f/128.0f) - mu.x*mu.x, 0.0f) + 1e-6f);
    rs.y = rsqrtf(fmaxf(q1*(1.0f/128.0f) - mu.y*mu.y, 0.0f) + 1e-6f);
    *(float2*)(muW + o) = mu;
    *(float2*)(rsW + o) = rs;
  } else if (gbid < 512) {
    const int bx = gbid - 256;
    const int side = bx >> 7, co = bx & 127;
    const float* W1  = side ? Wr1 : Wl1;
    const float* W2  = side ? Wr2 : Wl2;
    const float* b1  = side ? br1 : bl1;
    const float* lnw = side ? lnwr : lnwl;
    const float* lnb = side ? lnbr : lnbl;
    const int ci = t >> 1;
    const float lw = lnw[ci], lb = lnb[ci];

    const size_t dsto = (size_t)(side*32 + (t>>3))*8192 + (size_t)co*64 + (t&7)*8;

    const float* src1 = W1 + (size_t)co*2048 + t*8;
    const float4 a0 = *(const float4*)(src1);
    const float4 a1 = *(const float4*)(src1 + 4);
    float part = (a0.x+a0.y+a0.z+a0.w + a1.x+a1.y+a1.z+a1.w) * lb;
    uint4 pkq;
    pkq.x = pk2(a0.x*lw, a0.y*lw); pkq.y = pk2(a0.z*lw, a0.w*lw);
    pkq.z = pk2(a1.x*lw, a1.y*lw); pkq.w = pk2(a1.z*lw, a1.w*lw);
    *(uint4*)(Wq + dsto) = pkq;

    const float* src2 = W2 + (size_t)co*2048 + t*8;
    const float4 c0 = *(const float4*)(src2);
    const float4 c1 = *(const float4*)(src2 + 4);
    uint4 pkv;
    pkv.x = pk2(c0.x, c0.y); pkv.y = pk2(c0.z, c0.w);
    pkv.z = pk2(c1.x, c1.y); pkv.w = pk2(c1.z, c1.w);
    *(uint4*)(Wv + dsto) = pkv;

    float v = part;
    v += __shfl_down(v, 32, 64); v += __shfl_down(v, 16, 64);
    v += __shfl_down(v, 8, 64);  v += __shfl_down(v, 4, 64);
    v += __shfl_down(v, 2, 64);  v += __shfl_down(v, 1, 64);
    if ((t & 63) == 0) red[t >> 6] = v;
    __syncthreads();
    if (t == 0) bqW[side*128 + co] = b1[co] + red[0] + red[1] + red[2] + red[3];
  } else {
    const int b = gbid - 512;
    const float* src = (b < 256 ? Wl3 : Wr3) + (size_t)(b & 255) * 1024;
    const float4 v = *(const float4*)(src + t*4);
    *(uint2*)(W3bf + (size_t)b*1024 + t*4) = make_uint2(pk2(v.x, v.y), pk2(v.z, v.w));
  }
}

// ---------------- Kernel 2: conv GEMM, split-K x4, direct staging ----------------
__global__ __launch_bounds__(256) void k_conv(
    const float* __restrict__ xl, const float* __restrict__ xr,
    const unsigned short* __restrict__ Wq, const unsigned short* __restrict__ Wv,
    const float* __restrict__ muW, const float* __restrict__ rsW,
    unsigned short* __restrict__ Cpart)
{
  const int bid = blockIdx.x;
  const int ks = bid & 3;
  const int img = (bid >> 2) & 63;
  const int ctype = bid >> 8;
  const int side = ctype & 1;
  const bool isQ = ctype < 2;
  const float* x = (side ? xr : xl) + (size_t)img * 131072;
  const unsigned short* Bsrc = (isQ ? Wq : Wv) + (size_t)side * 262144;

  const int t = threadIdx.x;
  const int w = t >> 6, l = t & 63, lo = l & 15, g = l >> 4;

  __shared__ __align__(16) unsigned char lds[24576];
  unsigned char* A = lds;
  unsigned char* B = lds + 8192;

  const int cl   = t >> 6;
  const int px0  = (t & 63) * 16;
  const int y    = px0 >> 5;
  const int wr   = y & 3;
  const int pbase = (y >> 2)*8 + ((px0 & 31) >> 2);

  float4 mu4[4], rs4[4];
  if (isQ) {
    const int o = (side*64 + img)*1024 + px0;
#pragma unroll
    for (int i = 0; i < 4; ++i) {
      mu4[i] = *(const float4*)(muW + o + 4*i);
      rs4[i] = *(const float4*)(rsW + o + 4*i);
    }
  }

  const int cout = t >> 1, part = t & 1;
  const int keyB = ((cout ^ (cout >> 3)) & 7) << 4;

  f32x4 acc[4][2];
#pragma unroll
  for (int a = 0; a < 4; ++a) { acc[a][0] = (f32x4)0.0f; acc[a][1] = (f32x4)0.0f; }

  for (int it = 0; it < 8; ++it) {
    const int kb = ks*8 + it;
    __syncthreads();
    {
      const float* xs = x + (size_t)(kb*4 + cl)*1024 + px0;
#pragma unroll
      for (int i = 0; i < 4; ++i) {
        float4 v = *(const float4*)(xs + 4*i);
        if (isQ) {
          v.x = (v.x - mu4[i].x)*rs4[i].x; v.y = (v.y - mu4[i].y)*rs4[i].y;
          v.z = (v.z - mu4[i].z)*rs4[i].z; v.w = (v.w - mu4[i].w)*rs4[i].w;
        }
        const int p = pbase + i;
        int dst = p*128 + cl*32 + wr*8;
        dst ^= ((p ^ (p >> 3)) & 7) << 4;
        *(uint2*)(A + dst) = make_uint2(pk2(v.x, v.y), pk2(v.z, v.w));
      }
    }
    {
      const unsigned short* bs = Bsrc + (size_t)kb*8192 + t*32;
#pragma unroll
      for (int i = 0; i < 4; ++i) {
        const bf16x8 v = *(const bf16x8*)(bs + i*8);
        *(bf16x8*)(B + cout*128 + ((part*64 + i*16) ^ keyB)) = v;
      }
    }
    __syncthreads();
    bf16x8 af[4][2], bfr[2][2];
#pragma unroll
    for (int mf = 0; mf < 4; ++mf) {
      const int row = mf*16 + lo;
      const int key = ((row ^ (row >> 3)) & 7) << 4;
#pragma unroll
      for (int kc = 0; kc < 2; ++kc)
        af[mf][kc] = *(const bf16x8*)(A + row*128 + ((kc*64 + g*16) ^ key));
    }
#pragma unroll
    for (int nf = 0; nf < 2; ++nf) {
      const int row = w*32 + nf*16 + lo;
      const int key = ((row ^ (row >> 3)) & 7) << 4;
#pragma unroll
      for (int kc = 0; kc < 2; ++kc)
        bfr[nf][kc] = *(const bf16x8*)(B + row*128 + ((kc*64 + g*16) ^ key));
    }
    __builtin_amdgcn_s_setprio(1);
#pragma unroll
    for (int kc = 0; kc < 2; ++kc)
#pragma unroll
      for (int nf = 0; nf < 2; ++nf)
#pragma unroll
        for (int mf = 0; mf < 4; ++mf)
          acc[mf][nf] = mfma16(af[mf][kc], bfr[nf][kc], acc[mf][nf]);
    __builtin_amdgcn_s_setprio(0);
  }

  unsigned short* Cp = Cpart + (size_t)bid * 8192;
#pragma unroll
  for (int mf = 0; mf < 4; ++mf)
#pragma unroll
    for (int nf = 0; nf < 2; ++nf) {
      const int c = w*32 + nf*16 + lo;
      const int p0 = mf*16 + g*4;
      *(uint2*)(Cp + c*64 + p0) =
          make_uint2(pk2(acc[mf][nf][0], acc[mf][nf][1]),
                     pk2(acc[mf][nf][2], acc[mf][nf][3]));
    }
}

// ---------------- Kernel 2b: combine conv split-K partials ----------------
// Q scale includes log2(e) fold: sqrt-scale * log2(e) = 0.12625283
__global__ __launch_bounds__(256) void k_convred(
    const unsigned short* __restrict__ Cpart,
    const float* __restrict__ bqW,
    const float* __restrict__ bl2, const float* __restrict__ br2,
    const float* __restrict__ pos,
    unsigned short* __restrict__ Qbf, unsigned short* __restrict__ Vtbf)
{
  const int bid2 = blockIdx.x;
  const int ctype = bid2 >> 6, img = bid2 & 63;
  const int side = ctype & 1;
  const bool isQ = ctype < 2;
  const int t = threadIdx.x;

  __shared__ float S[64][130];

  const int c = t >> 1, p0 = (t & 1) * 32;
  {
    float acc[32];
#pragma unroll
    for (int j = 0; j < 32; ++j) acc[j] = 0.f;
#pragma unroll
    for (int s = 0; s < 4; ++s) {
      const unsigned short* Cp = Cpart + ((size_t)(bid2*4 + s))*8192 + c*64 + p0;
#pragma unroll
      for (int j8 = 0; j8 < 4; ++j8) {
        const bf16x8 v = *(const bf16x8*)(Cp + j8*8);
#pragma unroll
        for (int e = 0; e < 8; ++e)
          acc[j8*8 + e] += bf2f((unsigned short)v[e]);
      }
    }
#pragma unroll
    for (int j = 0; j < 32; ++j) S[p0 + j][c] = acc[j];
  }
  __syncthreads();

  if (isQ) {
    const float* bq = bqW + side*128;
    const int p = t >> 2, c0 = (t & 3) * 32;
    const int rot = (t & 3) * 4;
    uint32_t pk[16];
#pragma unroll
    for (int j2 = 0; j2 < 16; ++j2) {
      const int jj = (j2 + rot) & 15;
      const int ca = c0 + jj*2;
      const float2 sv = *(const float2*)(&S[p][ca]);
      const float va = (sv.x + bq[ca]     + pos[ca*64 + p])     * 0.12625283f;
      const float vb = (sv.y + bq[ca + 1] + pos[(ca+1)*64 + p]) * 0.12625283f;
      pk[jj] = pk2(va, vb);
    }
    unsigned short* Qo = Qbf + (size_t)side*524288 + ((size_t)(img*64 + p))*128 + c0;
    *(uint4*)(Qo)      = make_uint4(pk[0],  pk[1],  pk[2],  pk[3]);
    *(uint4*)(Qo + 8)  = make_uint4(pk[4],  pk[5],  pk[6],  pk[7]);
    *(uint4*)(Qo + 16) = make_uint4(pk[8],  pk[9],  pk[10], pk[11]);
    *(uint4*)(Qo + 24) = make_uint4(pk[12], pk[13], pk[14], pk[15]);
  } else {
    const float* b2 = side ? br2 : bl2;
    const float bb = b2[c];
    uint32_t pk[16];
#pragma unroll
    for (int j2 = 0; j2 < 16; ++j2) {
      const int pa = p0 + j2*2;
      const float va = S[pa][c]     + bb + pos[c*64 + pa];
      const float vb = S[pa + 1][c] + bb + pos[c*64 + pa + 1];
      pk[j2] = pk2(va, vb);
    }
    unsigned short* Vo = Vtbf + (size_t)side*524288 + (size_t)c*4096 + img*64 + p0;
    *(uint4*)(Vo)      = make_uint4(pk[0],  pk[1],  pk[2],  pk[3]);
    *(uint4*)(Vo + 8)  = make_uint4(pk[4],  pk[5],  pk[6],  pk[7]);
    *(uint4*)(Vo + 16) = make_uint4(pk[8],  pk[9],  pk[10], pk[11]);
    *(uint4*)(Vo + 24) = make_uint4(pk[12], pk[13], pk[14], pk[15]);
  }
}

// ---------------- Kernel 3: cross-attention, swapped QK^T, packed P-write ----------------
// grid 512 1-D; xcd=bid&7 -> dir=xcd>>2, ks=xcd&3 (pins each (dir,ks) to one XCD's L2).
__global__ __launch_bounds__(256, 2) void k_attn(
    const unsigned short* __restrict__ Qbf,
    const unsigned short* __restrict__ Vtbf,
    float* __restrict__ Opart,   // [2][64][4][64][128] f32
    float* __restrict__ Lpart)   // [2][64][4][64] f32
{
  const int bid = blockIdx.x;
  const int xcd = bid & 7;
  const int dir = xcd >> 2;
  const int ks  = xcd & 3;
  const int qb  = bid >> 3;
  const unsigned short* Qp = Qbf  + (size_t)dir*524288;
  const unsigned short* Kp = Qbf  + (size_t)(1-dir)*524288;
  const unsigned short* Vp = Vtbf + (size_t)(1-dir)*524288;

  const int t = threadIdx.x;
  const int w = t >> 6, l = t & 63, lo = l & 15, g = l >> 4;

  __shared__ __align__(16) unsigned char lds[73728];
  unsigned char* ldsP = lds + 65536;
  __shared__ float lred[4][64];

  bf16x8 aq[4][4];
#pragma unroll
  for (int mf = 0; mf < 4; ++mf)
#pragma unroll
    for (int kc = 0; kc < 4; ++kc)
      aq[mf][kc] = *(const bf16x8*)(Qp + (size_t)(qb*64 + mf*16 + lo)*128 + kc*32 + g*8);

  f32x4 o[4][2];
#pragma unroll
  for (int a = 0; a < 4; ++a) { o[a][0] = (f32x4)0.0f; o[a][1] = (f32x4)0.0f; }
  float ls[4] = {0.f, 0.f, 0.f, 0.f};

  const int kt0 = ks * 16;

  const int ksrcBase = t ^ ((t >> 4) & 7);
  const int vc    = t >> 3;
  const int vi16  = (t & 7) * 16;
  const int vsoff = (vi16 ^ (((t >> 3) & 7) << 4)) >> 1;

  {
    const uint4* src = (const uint4*)(Kp + (size_t)kt0*8192);
#pragma unroll
    for (int j = 0; j < 4; ++j)
      *(uint4*)(lds + (t + 256*j)*16) = src[ksrcBase + 256*j];
#pragma unroll
    for (int j = 0; j < 4; ++j) {
      const int c = vc + 32*j;
      *(uint4*)(lds + 32768 + c*128 + vi16) =
          *(const uint4*)(Vp + (size_t)c*4096 + kt0*64 + vsoff);
    }
  }
  __syncthreads();

  for (int it = 0; it < 16; ++it) {
    const int cur = it & 1;
    unsigned char* curK = lds + cur*16384;
    unsigned char* curV = lds + 32768 + cur*16384;

    uint4 kr0, kr1, kr2, kr3, vr0, vr1, vr2, vr3;
    if (it < 15) {
      const int kt = kt0 + it + 1;
      const uint4* src = (const uint4*)(Kp + (size_t)kt*8192);
      kr0 = src[ksrcBase];
      kr1 = src[ksrcBase + 256];
      kr2 = src[ksrcBase + 512];
      kr3 = src[ksrcBase + 768];
      const unsigned short* vsrc = Vp + (size_t)kt*64 + vsoff;
      vr0 = *(const uint4*)(vsrc + (size_t)(vc     )*4096);
      vr1 = *(const uint4*)(vsrc + (size_t)(vc + 32)*4096);
      vr2 = *(const uint4*)(vsrc + (size_t)(vc + 64)*4096);
      vr3 = *(const uint4*)(vsrc + (size_t)(vc + 96)*4096);
    }

    // QK^T (swapped: A=K rows, B=Q rows): s[mf] = S[k=w*16+g*4+rr][q=mf*16+lo]
    f32x4 s[4];
    s[0] = (f32x4)0.0f; s[1] = (f32x4)0.0f; s[2] = (f32x4)0.0f; s[3] = (f32x4)0.0f;
    const int krow = w*16 + lo;
    const int keyk = (krow & 7) << 4;
    __builtin_amdgcn_s_setprio(1);
#pragma unroll
    for (int kc = 0; kc < 4; ++kc) {
      const bf16x8 bk = *(const bf16x8*)(curK + krow*256 + ((kc*64 + g*16) ^ keyk));
#pragma unroll
      for (int mf = 0; mf < 4; ++mf)
        s[mf] = mfma16(bk, aq[mf][kc], s[mf]);
    }
    __builtin_amdgcn_s_setprio(0);

    // exp2 (log2e folded into Q scale), packed P write: P[q][k..k+3] per b64
#pragma unroll
    for (int mf = 0; mf < 4; ++mf) {
      const float e0 = exp2f(s[mf][0]);
      const float e1 = exp2f(s[mf][1]);
      const float e2 = exp2f(s[mf][2]);
      const float e3 = exp2f(s[mf][3]);
      ls[mf] += (e0 + e1) + (e2 + e3);
      const int q = mf*16 + lo;
      const int koff = (w*32 + g*8) ^ ((q & 7) << 4);
      *(uint2*)(ldsP + q*128 + koff) = make_uint2(pk2(e0, e1), pk2(e2, e3));
    }
    __syncthreads();

    // PV: O[q][c] += P[q][k] V[k][c]
    __builtin_amdgcn_s_setprio(1);
#pragma unroll
    for (int kd = 0; kd < 2; ++kd) {
      bf16x8 pa[4];
#pragma unroll
      for (int mf = 0; mf < 4; ++mf) {
        const int q = mf*16 + lo;
        pa[mf] = *(const bf16x8*)(ldsP + q*128 + ((kd*64 + g*16) ^ ((q & 7) << 4)));
      }
#pragma unroll
      for (int nf = 0; nf < 2; ++nf) {
        const int c = w*32 + nf*16 + lo;
        const bf16x8 bv = *(const bf16x8*)(curV + c*128 + ((kd*64 + g*16) ^ ((c & 7) << 4)));
#pragma unroll
        for (int mf = 0; mf < 4; ++mf)
          o[mf][nf] = mfma16(pa[mf], bv, o[mf][nf]);
      }
    }
    __builtin_amdgcn_s_setprio(0);

    if (it < 15) {
      unsigned char* nK = lds + (cur ^ 1)*16384;
      unsigned char* nV = lds + 32768 + (cur ^ 1)*16384;
      *(uint4*)(nK + (t      )*16) = kr0;
      *(uint4*)(nK + (t + 256)*16) = kr1;
      *(uint4*)(nK + (t + 512)*16) = kr2;
      *(uint4*)(nK + (t + 768)*16) = kr3;
      *(uint4*)(nV + (vc     )*128 + vi16) = vr0;
      *(uint4*)(nV + (vc + 32)*128 + vi16) = vr1;
      *(uint4*)(nV + (vc + 64)*128 + vi16) = vr2;
      *(uint4*)(nV + (vc + 96)*128 + vi16) = vr3;
    }
    __syncthreads();
  }

  // denominator: ls[mf] holds partial for q=mf*16+lo over this wave's 16 keys
#pragma unroll
  for (int mf = 0; mf < 4; ++mf) {
    float v = ls[mf];
    v += __shfl_xor(v, 16, 64);
    v += __shfl_xor(v, 32, 64);
    if (l < 16) lred[w][mf*16 + lo] = v;
  }
  __syncthreads();

  float* Ob = Opart + (((size_t)dir*64 + qb)*4 + ks)*64*128;
#pragma unroll
  for (int mf = 0; mf < 4; ++mf)
#pragma unroll
    for (int nf = 0; nf < 2; ++nf) {
      const int c = w*32 + nf*16 + lo;
#pragma unroll
      for (int rr = 0; rr < 4; ++rr) {
        const int q = mf*16 + g*4 + rr;
        Ob[q*128 + c] = o[mf][nf][rr];
      }
    }
  if (t < 64)
    Lpart[(((size_t)dir*64 + qb)*4 + ks)*64 + t] =
        lred[0][t] + lred[1][t] + lred[2][t] + lred[3][t];
}

// ---------------- Kernel 3b: combine split-K partials -> F bf16 ----------------
__global__ __launch_bounds__(256) void k_reduce(
    const float* __restrict__ Opart, const float* __restrict__ Lpart,
    unsigned short* __restrict__ Fbf)
{
  const int bid = blockIdx.x;
  const int dir = bid >> 7, rb = bid & 127;
  const int t = threadIdx.x;
  const int qr = t >> 3;
  const int cs = (t & 7) * 16;
  const int r  = rb*32 + qr;
  const int qb = r >> 6, q = r & 63;
  const size_t pb = ((size_t)dir*64 + qb)*4;
  float acc[16];
#pragma unroll
  for (int i = 0; i < 16; ++i) acc[i] = 0.f;
  float lsum = 0.f;
#pragma unroll
  for (int s = 0; s < 4; ++s) {
    const float* Ob = Opart + ((pb + s)*64 + q)*128 + cs;
#pragma unroll
    for (int i = 0; i < 16; i += 4) {
      const float4 v = *(const float4*)(Ob + i);
      acc[i] += v.x; acc[i+1] += v.y; acc[i+2] += v.z; acc[i+3] += v.w;
    }
    lsum += Lpart[(pb + s)*64 + q];
  }
  const float inv = 1.0f / lsum;
  uint32_t pkw[8];
#pragma unroll
  for (int i = 0; i < 8; ++i) pkw[i] = pk2(acc[2*i]*inv, acc[2*i+1]*inv);
  unsigned short* Fo = Fbf + (size_t)dir*524288 + (size_t)r*128 + cs;
  *(uint4*)(Fo)     = make_uint4(pkw[0], pkw[1], pkw[2], pkw[3]);
  *(uint4*)(Fo + 8) = make_uint4(pkw[4], pkw[5], pkw[6], pkw[7]);
}

// ---------------- Kernel 4: projection + pixel-shuffle + residual ----------------
__global__ __launch_bounds__(256) void k_proj(
    const unsigned short* __restrict__ Fbf,
    const unsigned short* __restrict__ W3bf,
    const float* __restrict__ bl3, const float* __restrict__ br3,
    const float* __restrict__ beta, const float* __restrict__ gamma,
    const float* __restrict__ xl, const float* __restrict__ xr,
    float* __restrict__ out)
{
  const int nb = blockIdx.x, mb = blockIdx.y, side = blockIdx.z;
  const unsigned short* F  = Fbf + (size_t)side*524288 + (size_t)mb*8192;
  const unsigned short* W3 = W3bf + (size_t)side*262144 + (size_t)nb*16384;
  const float* b3  = (side ? br3 : bl3) + nb*128;
  const float* scl = side ? gamma : beta;
  const float* xin = (side ? xr : xl) + (size_t)mb*131072;
  float* op = out + (size_t)side*8388608 + (size_t)mb*131072;

  const int t = threadIdx.x;
  const int w = t >> 6, l = t & 63, lo = l & 15, g = l >> 4;

  __shared__ __align__(16) unsigned char lds[49152];
  unsigned char* Ft = lds;
  unsigned char* B3 = lds + 16384;
  float* Sf = (float*)lds;

  {
    const uint4* src = (const uint4*)F;
#pragma unroll
    for (int j = 0; j < 4; ++j) {
      const int idx = t + 256*j;
      const int dst = idx*16;
      const int row = dst >> 8;
      *(uint4*)(Ft + dst) = src[(dst ^ ((row & 7) << 4)) >> 4];
    }
  }
  {
    const int nl = t >> 1, half = t & 1;
    const unsigned short* wsrc = W3 + (size_t)nl*128 + half*64;
#pragma unroll
    for (int ch = 0; ch < 8; ++ch) {
      const uint4 v = *(const uint4*)(wsrc + ch*8);
      const int inrow = (half*128 + ch*16) ^ ((nl & 7) << 4);
      *(uint4*)(B3 + nl*256 + inrow) = v;
    }
  }
  __syncthreads();

  f32x4 acc[4][2];
#pragma unroll
  for (int a=0;a<4;a++) { acc[a][0] = (f32x4)0.0f; acc[a][1] = (f32x4)0.0f; }

  bf16x8 af[4][4];
#pragma unroll
  for (int mf = 0; mf < 4; ++mf) {
    const int row = mf*16 + lo;
#pragma unroll
    for (int kc = 0; kc < 4; ++kc)
      af[mf][kc] = *(const bf16x8*)(Ft + row*256 + ((kc*64 + g*16) ^ ((row & 7) << 4)));
  }
#pragma unroll
  for (int kc = 0; kc < 4; ++kc)
#pragma unroll
    for (int nf = 0; nf < 2; ++nf) {
      const int n = w*32 + nf*16 + lo;
      const bf16x8 bb = *(const bf16x8*)(B3 + n*256 + ((kc*64 + g*16) ^ ((n & 7) << 4)));
#pragma unroll
      for (int mf = 0; mf < 4; ++mf)
        acc[mf][nf] = mfma16(af[mf][kc], bb, acc[mf][nf]);
    }

  __syncthreads();

  {
    const int r4 = (lo >> 2) & 3, sc = lo & 3;
#pragma unroll
    for (int nf = 0; nf < 2; ++nf) {
      const int cl = w*2 + nf;
      const int n16 = w*32 + nf*16 + lo;
      const float scc = scl[nb*8 + cl];
      const float bb3 = b3[n16];
#pragma unroll
      for (int mf = 0; mf < 4; ++mf)
#pragma unroll
        for (int rr = 0; rr < 4; ++rr) {
          const int pi = mf*16 + g*4 + rr;
          const int h = pi >> 3, wc = pi & 7;
          Sf[cl*1032 + h*128 + r4*32 + wc*4 + sc] = scc*(acc[mf][nf][rr] + bb3);
        }
    }
  }
  __syncthreads();

#pragma unroll
  for (int j = 0; j < 8; ++j) {
    const int pix = t*4;
    const float4 s = *(const float4*)(Sf + j*1032 + pix);
    const size_t gaddr = (size_t)(nb*8 + j)*1024 + pix;
    const float4 xv = *(const float4*)(xin + gaddr);
    float4 r;
    r.x = xv.x + s.x; r.y = xv.y + s.y; r.z = xv.z + s.z; r.w = xv.w + s.w;
    *(float4*)(op + gaddr) = r;
  }
}

extern "C" void kernel_launch(void* const* d_in, const int* in_sizes, int n_in,
                              void* d_out, int out_size, void* d_ws, size_t ws_size,
                              hipStream_t stream) {
  (void)in_sizes; (void)n_in; (void)out_size; (void)ws_size;
  const float* xl   = (const float*)d_in[0];
  const float* xr   = (const float*)d_in[1];
  const float* lnwl = (const float*)d_in[2];
  const float* lnbl = (const float*)d_in[3];
  const float* lnwr = (const float*)d_in[4];
  const float* lnbr = (const float*)d_in[5];
  const float* Wl1  = (const float*)d_in[6];
  const float* bl1  = (const float*)d_in[7];
  const float* Wr1  = (const float*)d_in[8];
  const float* br1  = (const float*)d_in[9];
  const float* Wl2  = (const float*)d_in[10];
  const float* bl2  = (const float*)d_in[11];
  const float* Wr2  = (const float*)d_in[12];
  const float* br2  = (const float*)d_in[13];
  const float* pos  = (const float*)d_in[14];
  const float* beta = (const float*)d_in[15];
  const float* gamma= (const float*)d_in[16];
  const float* Wl3  = (const float*)d_in[17];
  const float* bl3  = (const float*)d_in[18];
  const float* Wr3  = (const float*)d_in[19];
  const float* br3  = (const float*)d_in[20];

  float* muW = (float*)d_ws;                            // [2][64][1024]
  float* rsW = muW + 131072;                            // [2][64][1024]
  float* bqW = rsW + 131072;                            // [2][128]
  unsigned short* Wq   = (unsigned short*)(bqW + 256);  // [2][32][128][64]
  unsigned short* Wv   = Wq + 524288;                   // [2][32][128][64]
  unsigned short* Qbf  = Wv + 524288;                   // [2][4096][128]
  unsigned short* Vtbf = Qbf + 1048576;                 // [2][128][4096]
  unsigned short* Fbf  = Vtbf + 1048576;                // [2][4096][128]
  unsigned short* W3bf = Fbf + 1048576;                 // [2][2048][128]
  unsigned short* Cpart = W3bf + 524288;                // [1024][128][64] bf16 (16.8MB)
  float* Opart = (float*)Cpart;                         // alias: [2][64][4][64][128] f32
  float* Lpart = (float*)(Cpart + 8388608);             // [2][64][4][64] f32

  k_prep<<<1024, 256, 0, stream>>>(xl, xr, lnwl, lnbl, lnwr, lnbr,
      Wl1, bl1, Wr1, br1, Wl2, Wr2, Wl3, Wr3, muW, rsW, Wq, Wv, bqW, W3bf);
  k_conv<<<1024, 256, 0, stream>>>(xl, xr, Wq, Wv, muW, rsW, Cpart);
  k_convred<<<256, 256, 0, stream>>>(Cpart, bqW, bl2, br2, pos, Qbf, Vtbf);
  k_attn<<<512, 256, 0, stream>>>(Qbf, Vtbf, Opart, Lpart);
  k_reduce<<<256, 256, 0, stream>>>(Opart, Lpart, Fbf);
  k_proj<<<dim3(16, 64, 2), 256, 0, stream>>>(Fbf, W3bf, bl3, br3,
      beta, gamma, xl, xr, (float*)d_out);
}